// Round 1
// baseline (254.832 us; speedup 1.0000x reference)
//
#include <hip/hip_runtime.h>
#include <math.h>

// Problem constants (match reference setup_inputs)
constexpr int B = 2;
constexpr int N = 4096;
constexpr int C = 32;
constexpr int D = 256;
constexpr int K = 16;
constexpr int NW = N / 32;   // adjacency bitmask words per row = 128
constexpr int CAP = 128;     // max neighbors per row (16 out + in-degree; uniform data max ~50)
constexpr int ROWS = B * N;  // 8192

// ---------------------------------------------------------------------------
// Kernel 1: per-row preprocess: centers(+sqnorm), validity, feature inv-norm.
// One wave (64 lanes) per row: lanes do float4 loads of the 256-d feature row.
__global__ void pre_kernel(const float* __restrict__ rois,
                           const float* __restrict__ feats,
                           float4* __restrict__ centers4,
                           float* __restrict__ invnorm,
                           unsigned* __restrict__ validf) {
    const int t = threadIdx.x;
    const int wid = t >> 6, lane = t & 63;
    const int r = blockIdx.x * 4 + wid;
    if (r >= ROWS) return;

    const float4* f4 = reinterpret_cast<const float4*>(feats) + (size_t)r * (D / 4);
    float4 v = f4[lane];
    float ss = v.x * v.x + v.y * v.y + v.z * v.z + v.w * v.w;
#pragma unroll
    for (int off = 32; off; off >>= 1) ss += __shfl_xor(ss, off);

    if (lane == 0) {
        invnorm[r] = 1.0f / fmaxf(sqrtf(ss), 1e-6f);
        const float* rp = rois + (size_t)r * 6;
        float a0 = rp[0], a1 = rp[1], a2 = rp[2], a3 = rp[3], a4 = rp[4], a5 = rp[5];
        float cx = (a0 + a3) * 0.5f, cy = (a1 + a4) * 0.5f, cz = (a2 + a5) * 0.5f;
        float sq = cx * cx + cy * cy + cz * cz;
        centers4[r] = make_float4(cx, cy, cz, sq);
        float s = fabsf(a0) + fabsf(a1) + fabsf(a2) + fabsf(a3) + fabsf(a4) + fabsf(a5);
        validf[r] = (s > 0.0f) ? 1u : 0u;
    }
}

// ---------------------------------------------------------------------------
// Kernel 2: brute-force 16-NN per row. One block (256 thr) per row; each
// thread holds 16 candidate dists in regs; 16 rounds of block argmin with
// tie-break on smaller index (matches lax.top_k ordering). Selected edges
// set symmetric adjacency bits.
__global__ void knn_kernel(const float4* __restrict__ centers4,
                           const unsigned* __restrict__ validf,
                           unsigned* __restrict__ adj) {
    const int t = threadIdx.x;
    const int r = blockIdx.x;       // row = b*N + n
    const int n = r & (N - 1);
    const int base = r - n;         // b*N

    __shared__ float s_d[4];
    __shared__ int   s_i[4];
    __shared__ float s_fd;
    __shared__ int   s_fi;
    __shared__ int   s_sel[K];

    const float4 cq = centers4[r];
    const unsigned qv = validf[r];

    float d[16];
#pragma unroll
    for (int j = 0; j < 16; ++j) {
        int m = t + (j << 8);
        float4 cm = centers4[base + m];
        float dist = cq.w + cm.w - 2.0f * (cq.x * cm.x + cq.y * cm.y + cq.z * cm.z);
        dist = fmaxf(dist, 0.0f);
        bool bad = (!qv) || (!validf[base + m]) || (m == n);
        d[j] = bad ? INFINITY : dist;
    }

    int nsel = 0;
    for (int round = 0; round < K; ++round) {
        // per-thread argmin (ties: smaller j => smaller index, automatic)
        float bd = INFINITY; int bi = 0x7fffffff;
#pragma unroll
        for (int j = 0; j < 16; ++j) {
            if (d[j] < bd) { bd = d[j]; bi = t + (j << 8); }
        }
        // wave argmin
#pragma unroll
        for (int off = 32; off; off >>= 1) {
            float od = __shfl_xor(bd, off);
            int   oi = __shfl_xor(bi, off);
            if (od < bd || (od == bd && oi < bi)) { bd = od; bi = oi; }
        }
        if ((t & 63) == 0) { s_d[t >> 6] = bd; s_i[t >> 6] = bi; }
        __syncthreads();
        if (t == 0) {
            float fd = s_d[0]; int fi = s_i[0];
            for (int w = 1; w < 4; ++w) {
                float od = s_d[w]; int oi = s_i[w];
                if (od < fd || (od == fd && oi < fi)) { fd = od; fi = oi; }
            }
            s_fd = fd; s_fi = fi;
        }
        __syncthreads();
        float md = s_fd; int mi = s_fi;   // uniform
        if (md == INFINITY) break;        // uniform branch
        if (t == 0) s_sel[round] = mi;
        nsel = round + 1;
        if ((mi & 255) == t) {
            int jj = mi >> 8;
#pragma unroll
            for (int j = 0; j < 16; ++j) if (j == jj) d[j] = INFINITY;
        }
        __syncthreads();
    }
    __syncthreads();

    if (t < nsel) {
        int m = s_sel[t];
        atomicOr(&adj[(size_t)r * NW + (m >> 5)], 1u << (m & 31));
        atomicOr(&adj[(size_t)(base + m) * NW + (n >> 5)], 1u << (n & 31));
    }
}

// ---------------------------------------------------------------------------
// Kernel 3: build weighted neighbor lists from adjacency bits.
// One block per row. Ordered (ascending m) compaction for determinism, then
// one wave per neighbor computes the 256-d cosine dot + gaussian weight.
__global__ void build_kernel(const float* __restrict__ feats,
                             const float4* __restrict__ centers4,
                             const float* __restrict__ invnorm,
                             const unsigned* __restrict__ adj,
                             int* __restrict__ nbr_idx,
                             float* __restrict__ nbr_w,
                             int* __restrict__ nbr_cnt,
                             const float* __restrict__ raw_sigma) {
    const int t = threadIdx.x;
    const int r = blockIdx.x;
    const int n = r & (N - 1); (void)n;
    const int base = r - (r & (N - 1));

    __shared__ int    s_off[NW];
    __shared__ int    s_list[CAP];
    __shared__ float  s_w[CAP];
    __shared__ float4 s_fq[D / 4];
    __shared__ int    s_cnt;
    __shared__ float  s_sum;

    const float4* fq4 = reinterpret_cast<const float4*>(feats) + (size_t)r * (D / 4);
    if (t < D / 4) s_fq[t] = fq4[t];

    unsigned word = 0;
    if (t < NW) {
        word = adj[(size_t)r * NW + t];
        s_off[t] = __popc(word);
    }
    __syncthreads();
    if (t == 0) {
        int run = 0;
        for (int i = 0; i < NW; ++i) { int c = s_off[i]; s_off[i] = run; run += c; }
        s_cnt = run > CAP ? CAP : run;
    }
    __syncthreads();
    const int cnt = s_cnt;
    if (t < NW && word) {
        int o = s_off[t];
        unsigned w2 = word;
        while (w2) {
            int bit = __ffs(w2) - 1;
            if (o < CAP) s_list[o] = t * 32 + bit;
            ++o;
            w2 &= w2 - 1;
        }
    }
    __syncthreads();

    const float rs = raw_sigma[0];
    const float sigma = fmaxf(log1pf(expf(rs)), 1e-6f);
    const float nhalf_inv_s2 = -0.5f / (sigma * sigma);

    const int wid = t >> 6, lane = t & 63;
    const float inq = invnorm[r];
    const float4 cq = centers4[r];

    for (int i = wid; i < cnt; i += 4) {
        int m = s_list[i];
        int gm = base + m;
        float4 fm = reinterpret_cast<const float4*>(feats)[(size_t)gm * (D / 4) + lane];
        float4 fq = s_fq[lane];
        float p = fm.x * fq.x + fm.y * fq.y + fm.z * fq.z + fm.w * fq.w;
#pragma unroll
        for (int off = 32; off; off >>= 1) p += __shfl_xor(p, off);
        if (lane == 0) {
            float cosv = p * inq * invnorm[gm];
            float aff = fminf(fmaxf((cosv + 1.0f) * 0.5f, 0.0f), 1.0f);
            float4 cm = centers4[gm];
            float dist = fmaxf(cq.w + cm.w - 2.0f * (cq.x * cm.x + cq.y * cm.y + cq.z * cm.z), 0.0f);
            s_w[i] = expf(dist * nhalf_inv_s2) * aff;
        }
    }
    __syncthreads();
    if (t == 0) {
        float sum = 0.0f;
        for (int i = 0; i < cnt; ++i) sum += s_w[i];
        s_sum = fmaxf(sum, 1e-6f);
    }
    __syncthreads();
    for (int i = t; i < cnt; i += 256) {
        nbr_idx[(size_t)r * CAP + i] = s_list[i];
        nbr_w[(size_t)r * CAP + i]   = s_w[i] / s_sum;
    }
    if (t == 0) nbr_cnt[r] = cnt;
}

// ---------------------------------------------------------------------------
// Kernel 4: q = softmax(logits) rows. 32 lanes per row, 8 rows per block.
__global__ void softmax_kernel(const float* __restrict__ logits, float* __restrict__ q) {
    const int t = threadIdx.x;
    const int r = blockIdx.x * 8 + (t >> 5);
    const int c = t & 31;
    float x = logits[(size_t)r * C + c];
    float mx = x;
#pragma unroll
    for (int off = 16; off; off >>= 1) mx = fmaxf(mx, __shfl_xor(mx, off, 32));
    float e = expf(x - mx);
    float s = e;
#pragma unroll
    for (int off = 16; off; off >>= 1) s += __shfl_xor(s, off, 32);
    q[(size_t)r * C + c] = e / s;
}

// ---------------------------------------------------------------------------
// Kernel 5: one mean-field iteration. 32 lanes per row (class c per lane).
// pairwise via moments of the (c-d)^2/961 compat matrix.
__global__ void iter_kernel(const float* __restrict__ logits,
                            const int* __restrict__ nbr_idx,
                            const float* __restrict__ nbr_w,
                            const int* __restrict__ nbr_cnt,
                            const float* __restrict__ q_in,
                            float* __restrict__ q_out,
                            float* __restrict__ refined_out,
                            const float* __restrict__ raw_smooth,
                            int write_refined) {
    const int t = threadIdx.x;
    const int r = blockIdx.x * 8 + (t >> 5);
    const int c = t & 31;
    const int base = r - (r & (N - 1));
    const float smooth = log1pf(expf(raw_smooth[0]));

    const int cnt = nbr_cnt[r];
    const int*   ip = nbr_idx + (size_t)r * CAP;
    const float* wp = nbr_w  + (size_t)r * CAP;

    float qn = 0.0f;
    for (int j = 0; j < cnt; ++j) {
        int m = ip[j];
        float w = wp[j];
        qn += w * q_in[(size_t)(base + m) * C + c];
    }

    const float fc = (float)c;
    float m0 = qn, m1 = qn * fc, m2 = qn * fc * fc;
#pragma unroll
    for (int off = 16; off; off >>= 1) {
        m0 += __shfl_xor(m0, off, 32);
        m1 += __shfl_xor(m1, off, 32);
        m2 += __shfl_xor(m2, off, 32);
    }
    float pw = (m2 - 2.0f * fc * m1 + fc * fc * m0) * (1.0f / 961.0f);
    float refined = logits[(size_t)r * C + c] - smooth * pw;
    if (write_refined) refined_out[(size_t)r * C + c] = refined;

    float mx = refined;
#pragma unroll
    for (int off = 16; off; off >>= 1) mx = fmaxf(mx, __shfl_xor(mx, off, 32));
    float e = expf(refined - mx);
    float s = e;
#pragma unroll
    for (int off = 16; off; off >>= 1) s += __shfl_xor(s, off, 32);
    q_out[(size_t)r * C + c] = e / s;
}

// ---------------------------------------------------------------------------
extern "C" void kernel_launch(void* const* d_in, const int* in_sizes, int n_in,
                              void* d_out, int out_size, void* d_ws, size_t ws_size,
                              hipStream_t stream) {
    const float* logits     = (const float*)d_in[0];
    const float* rois       = (const float*)d_in[1];
    const float* feats      = (const float*)d_in[2];
    const float* raw_sigma  = (const float*)d_in[3];
    const float* raw_smooth = (const float*)d_in[4];
    float* out = (float*)d_out;

    char* ws = (char*)d_ws;
    size_t off = 0;
    auto alloc = [&](size_t bytes) -> void* {
        void* p = ws + off;
        off += (bytes + 255) & ~(size_t)255;
        return p;
    };
    float4*   centers4 = (float4*)  alloc((size_t)ROWS * sizeof(float4));
    float*    invnorm  = (float*)   alloc((size_t)ROWS * 4);
    unsigned* validf   = (unsigned*)alloc((size_t)ROWS * 4);
    unsigned* adj      = (unsigned*)alloc((size_t)ROWS * NW * 4);
    int*      nbr_idx  = (int*)     alloc((size_t)ROWS * CAP * 4);
    float*    nbr_w    = (float*)   alloc((size_t)ROWS * CAP * 4);
    int*      nbr_cnt  = (int*)     alloc((size_t)ROWS * 4);
    float*    q_a      = (float*)   alloc((size_t)ROWS * C * 4);
    float*    q_b      = (float*)   alloc((size_t)ROWS * C * 4);

    hipMemsetAsync(adj, 0, (size_t)ROWS * NW * 4, stream);
    pre_kernel<<<ROWS / 4, 256, 0, stream>>>(rois, feats, centers4, invnorm, validf);
    knn_kernel<<<ROWS, 256, 0, stream>>>(centers4, validf, adj);
    build_kernel<<<ROWS, 256, 0, stream>>>(feats, centers4, invnorm, adj,
                                           nbr_idx, nbr_w, nbr_cnt, raw_sigma);
    softmax_kernel<<<ROWS / 8, 256, 0, stream>>>(logits, q_a);

    float* qi = q_a;
    float* qo = q_b;
    for (int it = 0; it < 5; ++it) {
        iter_kernel<<<ROWS / 8, 256, 0, stream>>>(logits, nbr_idx, nbr_w, nbr_cnt,
                                                  qi, qo, out, raw_smooth,
                                                  (it == 4) ? 1 : 0);
        float* tmp = qi; qi = qo; qo = tmp;
    }
}

// Round 2
// 234.530 us; speedup vs baseline: 1.0866x; 1.0866x over previous
//
#include <hip/hip_runtime.h>
#include <math.h>

// Problem constants (match reference setup_inputs)
constexpr int B = 2;
constexpr int N = 4096;
constexpr int C = 32;
constexpr int D = 256;
constexpr int K = 16;
constexpr int NW = N / 32;   // adjacency bitmask words per row = 128
constexpr int CAP = 128;     // max neighbors per row (16 out + in-degree)
constexpr int ROWS = B * N;  // 8192

// ---------------------------------------------------------------------------
// Kernel 1: per-row preprocess: centers(+sqnorm or INF if invalid), feature
// inv-norm. One wave (64 lanes) per row.
__global__ void pre_kernel(const float* __restrict__ rois,
                           const float* __restrict__ feats,
                           float4* __restrict__ centers4,
                           float* __restrict__ invnorm) {
    const int t = threadIdx.x;
    const int wid = t >> 6, lane = t & 63;
    const int r = blockIdx.x * 4 + wid;
    if (r >= ROWS) return;

    const float4* f4 = reinterpret_cast<const float4*>(feats) + (size_t)r * (D / 4);
    float4 v = f4[lane];
    float ss = v.x * v.x + v.y * v.y + v.z * v.z + v.w * v.w;
#pragma unroll
    for (int off = 32; off; off >>= 1) ss += __shfl_xor(ss, off);

    if (lane == 0) {
        invnorm[r] = 1.0f / fmaxf(sqrtf(ss), 1e-6f);
        const float* rp = rois + (size_t)r * 6;
        float a0 = rp[0], a1 = rp[1], a2 = rp[2], a3 = rp[3], a4 = rp[4], a5 = rp[5];
        float cx = (a0 + a3) * 0.5f, cy = (a1 + a4) * 0.5f, cz = (a2 + a5) * 0.5f;
        float sq = cx * cx + cy * cy + cz * cz;
        float s = fabsf(a0) + fabsf(a1) + fabsf(a2) + fabsf(a3) + fabsf(a4) + fabsf(a5);
        centers4[r] = make_float4(cx, cy, cz, (s > 0.0f) ? sq : INFINITY);
    }
}

// ---------------------------------------------------------------------------
// Kernel 2: brute-force 16-NN, ONE WAVE PER ROW. Each lane owns 64 candidates
// (m = lane + 64*j), keeps dists in registers plus a cached top-2. 16 rounds
// of wave-argmin over packed u64 keys (dist_bits<<32 | index, so tie-break on
// smaller index is free). First extraction per lane promotes its 2nd-min;
// repeat extraction triggers a (rare) full rescan gated by __any.
__global__ void knn_kernel(const float4* __restrict__ centers4,
                           unsigned* __restrict__ adj) {
    const int t = threadIdx.x;
    const int lane = t & 63;
    const int r = blockIdx.x * 4 + (t >> 6);
    const int n = r & (N - 1);
    const int base = r - n;

    const float4 cq = centers4[r];

    float d[64];
    float bd1 = INFINITY; int bj1 = 0;
#pragma unroll
    for (int j = 0; j < 64; ++j) {
        const int m = lane + (j << 6);
        float4 cm = centers4[base + m];
        float dist = fmaxf(cq.w + cm.w - 2.0f * (cq.x * cm.x + cq.y * cm.y + cq.z * cm.z), 0.0f);
        dist = (m == n) ? INFINITY : dist;
        d[j] = dist;
        if (dist < bd1) { bd1 = dist; bj1 = j; }
    }
    // second-smallest per lane
    float bd2 = INFINITY; int bj2 = 0;
#pragma unroll
    for (int j = 0; j < 64; ++j) {
        float dj = (j == bj1) ? INFINITY : d[j];
        if (dj < bd2) { bd2 = dj; bj2 = j; }
    }
    bool have2 = true;

    unsigned long long removed = 0ull;
    const unsigned long long KINF = (unsigned long long)0x7F800000u << 32;
    int my_sel = -1;

    for (int round = 0; round < K; ++round) {
        // packed key for this lane's current min
        unsigned long long k =
            ((unsigned long long)__float_as_uint(bd1) << 32) | (unsigned)(lane + (bj1 << 6));
#pragma unroll
        for (int off = 32; off; off >>= 1) {
            unsigned long long o = __shfl_xor(k, off);
            k = (o < k) ? o : k;
        }
        if (k >= KINF) break;                 // uniform: no finite candidates left
        const int wm = (int)(unsigned)k;      // winner global index within batch
        if (lane == round) my_sel = wm;

        if ((wm & 63) == lane) {              // this lane owned the winner
            removed |= 1ull << bj1;
            if (have2) { bd1 = bd2; bj1 = bj2; have2 = false; }
            else       { bd1 = -1.0f; }       // sentinel: needs rescan
        }
        const bool need = ((wm & 63) == lane) && (bd1 < 0.0f);
        if (__any(need)) {
            if (need) {
                float nb1 = INFINITY, nb2 = INFINITY; int nj1 = 0, nj2 = 0;
#pragma unroll
                for (int j = 0; j < 64; ++j) {
                    float dj = ((removed >> j) & 1ull) ? INFINITY : d[j];
                    if (dj < nb1) { nb2 = nb1; nj2 = nj1; nb1 = dj; nj1 = j; }
                    else if (dj < nb2) { nb2 = dj; nj2 = j; }
                }
                bd1 = nb1; bj1 = nj1; bd2 = nb2; bj2 = nj2;
                have2 = (nb2 < INFINITY);
            }
        }
    }

    if (my_sel >= 0) {
        const int m = my_sel;
        atomicOr(&adj[(size_t)r * NW + (m >> 5)], 1u << (m & 31));
        atomicOr(&adj[(size_t)(base + m) * NW + (n >> 5)], 1u << (n & 31));
    }
}

// ---------------------------------------------------------------------------
// Kernel 3: build weighted neighbor lists from adjacency bits.
__global__ void build_kernel(const float* __restrict__ feats,
                             const float4* __restrict__ centers4,
                             const float* __restrict__ invnorm,
                             const unsigned* __restrict__ adj,
                             int* __restrict__ nbr_idx,
                             float* __restrict__ nbr_w,
                             int* __restrict__ nbr_cnt,
                             const float* __restrict__ raw_sigma) {
    const int t = threadIdx.x;
    const int r = blockIdx.x;
    const int base = r - (r & (N - 1));

    __shared__ int    s_off[NW];
    __shared__ int    s_list[CAP];
    __shared__ float  s_w[CAP];
    __shared__ float4 s_fq[D / 4];
    __shared__ int    s_cnt;
    __shared__ float  s_sum;

    const float4* fq4 = reinterpret_cast<const float4*>(feats) + (size_t)r * (D / 4);
    if (t < D / 4) s_fq[t] = fq4[t];

    unsigned word = 0;
    if (t < NW) {
        word = adj[(size_t)r * NW + t];
        s_off[t] = __popc(word);
    }
    __syncthreads();
    if (t == 0) {
        int run = 0;
        for (int i = 0; i < NW; ++i) { int c = s_off[i]; s_off[i] = run; run += c; }
        s_cnt = run > CAP ? CAP : run;
    }
    __syncthreads();
    const int cnt = s_cnt;
    if (t < NW && word) {
        int o = s_off[t];
        unsigned w2 = word;
        while (w2) {
            int bit = __ffs(w2) - 1;
            if (o < CAP) s_list[o] = t * 32 + bit;
            ++o;
            w2 &= w2 - 1;
        }
    }
    __syncthreads();

    const float rs = raw_sigma[0];
    const float sigma = fmaxf(log1pf(expf(rs)), 1e-6f);
    const float nhalf_inv_s2 = -0.5f / (sigma * sigma);

    const int wid = t >> 6, lane = t & 63;
    const float inq = invnorm[r];
    const float4 cq = centers4[r];

    for (int i = wid; i < cnt; i += 4) {
        int m = s_list[i];
        int gm = base + m;
        float4 fm = reinterpret_cast<const float4*>(feats)[(size_t)gm * (D / 4) + lane];
        float4 fq = s_fq[lane];
        float p = fm.x * fq.x + fm.y * fq.y + fm.z * fq.z + fm.w * fq.w;
#pragma unroll
        for (int off = 32; off; off >>= 1) p += __shfl_xor(p, off);
        if (lane == 0) {
            float cosv = p * inq * invnorm[gm];
            float aff = fminf(fmaxf((cosv + 1.0f) * 0.5f, 0.0f), 1.0f);
            float4 cm = centers4[gm];
            float dist = fmaxf(cq.w + cm.w - 2.0f * (cq.x * cm.x + cq.y * cm.y + cq.z * cm.z), 0.0f);
            s_w[i] = expf(dist * nhalf_inv_s2) * aff;
        }
    }
    __syncthreads();
    if (t == 0) {
        float sum = 0.0f;
        for (int i = 0; i < cnt; ++i) sum += s_w[i];
        s_sum = fmaxf(sum, 1e-6f);
    }
    __syncthreads();
    for (int i = t; i < cnt; i += 256) {
        nbr_idx[(size_t)r * CAP + i] = s_list[i];
        nbr_w[(size_t)r * CAP + i]   = s_w[i] / s_sum;
    }
    if (t == 0) nbr_cnt[r] = cnt;
}

// ---------------------------------------------------------------------------
// Kernel 4: q = softmax(logits) rows. 32 lanes per row, 8 rows per block.
__global__ void softmax_kernel(const float* __restrict__ logits, float* __restrict__ q) {
    const int t = threadIdx.x;
    const int r = blockIdx.x * 8 + (t >> 5);
    const int c = t & 31;
    float x = logits[(size_t)r * C + c];
    float mx = x;
#pragma unroll
    for (int off = 16; off; off >>= 1) mx = fmaxf(mx, __shfl_xor(mx, off, 32));
    float e = expf(x - mx);
    float s = e;
#pragma unroll
    for (int off = 16; off; off >>= 1) s += __shfl_xor(s, off, 32);
    q[(size_t)r * C + c] = e / s;
}

// ---------------------------------------------------------------------------
// Kernel 5: one mean-field iteration. 32 lanes per row (class c per lane).
__global__ void iter_kernel(const float* __restrict__ logits,
                            const int* __restrict__ nbr_idx,
                            const float* __restrict__ nbr_w,
                            const int* __restrict__ nbr_cnt,
                            const float* __restrict__ q_in,
                            float* __restrict__ q_out,
                            float* __restrict__ refined_out,
                            const float* __restrict__ raw_smooth,
                            int write_refined) {
    const int t = threadIdx.x;
    const int r = blockIdx.x * 8 + (t >> 5);
    const int c = t & 31;
    const int base = r - (r & (N - 1));
    const float smooth = log1pf(expf(raw_smooth[0]));

    const int cnt = nbr_cnt[r];
    const int*   ip = nbr_idx + (size_t)r * CAP;
    const float* wp = nbr_w  + (size_t)r * CAP;

    float qn = 0.0f;
    for (int j = 0; j < cnt; ++j) {
        int m = ip[j];
        float w = wp[j];
        qn += w * q_in[(size_t)(base + m) * C + c];
    }

    const float fc = (float)c;
    float m0 = qn, m1 = qn * fc, m2 = qn * fc * fc;
#pragma unroll
    for (int off = 16; off; off >>= 1) {
        m0 += __shfl_xor(m0, off, 32);
        m1 += __shfl_xor(m1, off, 32);
        m2 += __shfl_xor(m2, off, 32);
    }
    float pw = (m2 - 2.0f * fc * m1 + fc * fc * m0) * (1.0f / 961.0f);
    float refined = logits[(size_t)r * C + c] - smooth * pw;
    if (write_refined) refined_out[(size_t)r * C + c] = refined;

    float mx = refined;
#pragma unroll
    for (int off = 16; off; off >>= 1) mx = fmaxf(mx, __shfl_xor(mx, off, 32));
    float e = expf(refined - mx);
    float s = e;
#pragma unroll
    for (int off = 16; off; off >>= 1) s += __shfl_xor(s, off, 32);
    q_out[(size_t)r * C + c] = e / s;
}

// ---------------------------------------------------------------------------
extern "C" void kernel_launch(void* const* d_in, const int* in_sizes, int n_in,
                              void* d_out, int out_size, void* d_ws, size_t ws_size,
                              hipStream_t stream) {
    const float* logits     = (const float*)d_in[0];
    const float* rois       = (const float*)d_in[1];
    const float* feats      = (const float*)d_in[2];
    const float* raw_sigma  = (const float*)d_in[3];
    const float* raw_smooth = (const float*)d_in[4];
    float* out = (float*)d_out;

    char* ws = (char*)d_ws;
    size_t off = 0;
    auto alloc = [&](size_t bytes) -> void* {
        void* p = ws + off;
        off += (bytes + 255) & ~(size_t)255;
        return p;
    };
    float4*   centers4 = (float4*)  alloc((size_t)ROWS * sizeof(float4));
    float*    invnorm  = (float*)   alloc((size_t)ROWS * 4);
    unsigned* adj      = (unsigned*)alloc((size_t)ROWS * NW * 4);
    int*      nbr_idx  = (int*)     alloc((size_t)ROWS * CAP * 4);
    float*    nbr_w    = (float*)   alloc((size_t)ROWS * CAP * 4);
    int*      nbr_cnt  = (int*)     alloc((size_t)ROWS * 4);
    float*    q_a      = (float*)   alloc((size_t)ROWS * C * 4);
    float*    q_b      = (float*)   alloc((size_t)ROWS * C * 4);

    hipMemsetAsync(adj, 0, (size_t)ROWS * NW * 4, stream);
    pre_kernel<<<ROWS / 4, 256, 0, stream>>>(rois, feats, centers4, invnorm);
    knn_kernel<<<ROWS / 4, 256, 0, stream>>>(centers4, adj);
    build_kernel<<<ROWS, 256, 0, stream>>>(feats, centers4, invnorm, adj,
                                           nbr_idx, nbr_w, nbr_cnt, raw_sigma);
    softmax_kernel<<<ROWS / 8, 256, 0, stream>>>(logits, q_a);

    float* qi = q_a;
    float* qo = q_b;
    for (int it = 0; it < 5; ++it) {
        iter_kernel<<<ROWS / 8, 256, 0, stream>>>(logits, nbr_idx, nbr_w, nbr_cnt,
                                                  qi, qo, out, raw_smooth,
                                                  (it == 4) ? 1 : 0);
        float* tmp = qi; qi = qo; qo = tmp;
    }
}